// Round 2
// baseline (765.669 us; speedup 1.0000x reference)
//
#include <hip/hip_runtime.h>
#include <math.h>

// Problem constants
#define BATCH 8
#define CDIM 512       // DIM
#define XY 1024        // X*Y = 32*32
#define NCTX 1024
#define HEADS 8
#define DHEAD 64
#define EINNER 512     // HEADS*DHEAD
#define E2 1024        // 2*EINNER

#define SQRT_DIM 22.627416997969522f  // sqrt(512)

// ---------------------------------------------------------------------------
// Kernel 1: per-(b,xy) channel-RMSNorm scale for fmap  [b][c][xy] layout
// scale = sqrt(512) / max(||x_c||, eps);  gamma applied at GEMM B-load.
// ---------------------------------------------------------------------------
__global__ __launch_bounds__(256) void k_fmap_scale(const float* __restrict__ fmap,
                                                    float* __restrict__ fscale) {
    int t = blockIdx.x * 256 + threadIdx.x;       // 0..8191 = B*XY
    int b = t >> 10, xy = t & 1023;
    const float* p = fmap + (size_t)b * CDIM * XY + xy;
    float ss = 0.f;
#pragma unroll 8
    for (int c = 0; c < CDIM; ++c) {
        float v = p[(size_t)c * XY];              // consecutive lanes -> consecutive xy
        ss = fmaf(v, v, ss);
    }
    fscale[t] = SQRT_DIM / fmaxf(sqrtf(ss), 1e-12f);
}

// ---------------------------------------------------------------------------
// Kernel 2: per-(b,n) RMSNorm scale for context [b][n][c] (c contiguous)
// one wave per row
// ---------------------------------------------------------------------------
__global__ __launch_bounds__(256) void k_ctx_scale(const float* __restrict__ ctx,
                                                   float* __restrict__ cscale) {
    int row = blockIdx.x * 4 + (threadIdx.x >> 6);   // B*N rows
    int lane = threadIdx.x & 63;
    const float* p = ctx + (size_t)row * CDIM;
    float ss = 0.f;
#pragma unroll
    for (int k = 0; k < CDIM / 64; ++k) {
        float v = p[lane + 64 * k];
        ss = fmaf(v, v, ss);
    }
#pragma unroll
    for (int off = 32; off; off >>= 1) ss += __shfl_down(ss, off, 64);
    if (lane == 0) cscale[row] = SQRT_DIM / fmaxf(sqrtf(ss), 1e-12f);
}

// ---------------------------------------------------------------------------
// GEMM NN: C[b][m][n] = sum_k A[m][k] * Bop[b][k][n]
// A unbatched (weights, row-major [M][K]); B batched row-major [K][N].
// If SCALE_B: Bop element (k,n) *= colscale[b*N + n] * rowgamma[k]
// 64x64 tile, BK=16, 256 threads, 4x4 micro-tile.
// ---------------------------------------------------------------------------
template <bool SCALE_B>
__global__ __launch_bounds__(256) void k_gemm_nn(const float* __restrict__ A,
                                                 const float* __restrict__ Bm,
                                                 float* __restrict__ Cm,
                                                 const float* __restrict__ colscale,
                                                 const float* __restrict__ rowgamma,
                                                 int M, int N, int K) {
    const int b = blockIdx.z;
    const int n0 = blockIdx.x * 64, m0 = blockIdx.y * 64;
    const float* Bb = Bm + (size_t)b * K * N;
    float* Cb = Cm + (size_t)b * M * N;
    __shared__ float As[16][68];
    __shared__ float Bs[16][68];
    const int t = threadIdx.x;
    const int tr = t >> 4, tc = t & 15;
    const int la_k = t & 15, la_m = t >> 4;   // A loader: (m = la_m+16i, k = la_k)
    const int lb_n = t & 63, lb_k = t >> 6;   // B loader: (k = lb_k+4i, n = lb_n)
    float acc[4][4] = {};

    // loop-invariant: per-column scale (hoisted out of K-loop)
    float cs = 1.f;
    if constexpr (SCALE_B) cs = colscale[(size_t)b * N + n0 + lb_n];

    for (int k0 = 0; k0 < K; k0 += 16) {
        __syncthreads();
#pragma unroll
        for (int i = 0; i < 4; ++i) {
            int m = la_m + 16 * i;
            As[la_k][m] = A[(size_t)(m0 + m) * K + k0 + la_k];
        }
#pragma unroll
        for (int i = 0; i < 4; ++i) {
            int kk = lb_k + 4 * i;
            float v = Bb[(size_t)(k0 + kk) * N + n0 + lb_n];
            if constexpr (SCALE_B)
                v *= cs * rowgamma[k0 + kk];
            Bs[kk][lb_n] = v;
        }
        __syncthreads();
#pragma unroll
        for (int kk = 0; kk < 16; ++kk) {
            const float4 a4 = *(const float4*)(&As[kk][tr * 4]);
            const float4 b4 = *(const float4*)(&Bs[kk][tc * 4]);
            const float ar[4] = {a4.x, a4.y, a4.z, a4.w};
            const float bc[4] = {b4.x, b4.y, b4.z, b4.w};
#pragma unroll
            for (int rr = 0; rr < 4; ++rr)
#pragma unroll
                for (int cc = 0; cc < 4; ++cc)
                    acc[rr][cc] = fmaf(ar[rr], bc[cc], acc[rr][cc]);
        }
    }
#pragma unroll
    for (int rr = 0; rr < 4; ++rr) {
        float4 v = {acc[rr][0], acc[rr][1], acc[rr][2], acc[rr][3]};
        *(float4*)(&Cb[(size_t)(m0 + tr * 4 + rr) * N + n0 + tc * 4]) = v;
    }
}

// ---------------------------------------------------------------------------
// GEMM NT: C[b][m][n] = sum_k Aop[b][m][k] * B[n][k]
// A batched row-major [M][K] with per-row scale + per-k gamma; B unbatched [N][K].
// ---------------------------------------------------------------------------
__global__ __launch_bounds__(256) void k_gemm_nt(const float* __restrict__ Am,
                                                 const float* __restrict__ Bmat,
                                                 float* __restrict__ Cm,
                                                 const float* __restrict__ rowscale,
                                                 const float* __restrict__ kgamma,
                                                 int M, int N, int K) {
    const int b = blockIdx.z;
    const int n0 = blockIdx.x * 64, m0 = blockIdx.y * 64;
    const float* Ab = Am + (size_t)b * M * K;
    float* Cb = Cm + (size_t)b * M * N;
    __shared__ float As[16][68];
    __shared__ float Bs[16][68];
    const int t = threadIdx.x;
    const int tr = t >> 4, tc = t & 15;
    const int la_k = t & 15, la_m = t >> 4;
    float acc[4][4] = {};

    // loop-invariant: per-row scale (4 rows/thread loader), hoisted
    float rs[4];
#pragma unroll
    for (int i = 0; i < 4; ++i)
        rs[i] = rowscale[(size_t)b * M + m0 + la_m + 16 * i];

    for (int k0 = 0; k0 < K; k0 += 16) {
        __syncthreads();
#pragma unroll
        for (int i = 0; i < 4; ++i) {
            int m = la_m + 16 * i;
            float v = Ab[(size_t)(m0 + m) * K + k0 + la_k];
            v *= rs[i] * kgamma[k0 + la_k];
            As[la_k][m] = v;
        }
#pragma unroll
        for (int i = 0; i < 4; ++i) {
            int n = la_m + 16 * i;
            Bs[la_k][n] = Bmat[(size_t)(n0 + n) * K + k0 + la_k];
        }
        __syncthreads();
#pragma unroll
        for (int kk = 0; kk < 16; ++kk) {
            const float4 a4 = *(const float4*)(&As[kk][tr * 4]);
            const float4 b4 = *(const float4*)(&Bs[kk][tc * 4]);
            const float ar[4] = {a4.x, a4.y, a4.z, a4.w};
            const float bc[4] = {b4.x, b4.y, b4.z, b4.w};
#pragma unroll
            for (int rr = 0; rr < 4; ++rr)
#pragma unroll
                for (int cc = 0; cc < 4; ++cc)
                    acc[rr][cc] = fmaf(ar[rr], bc[cc], acc[rr][cc]);
        }
    }
#pragma unroll
    for (int rr = 0; rr < 4; ++rr) {
        float4 v = {acc[rr][0], acc[rr][1], acc[rr][2], acc[rr][3]};
        *(float4*)(&Cb[(size_t)(m0 + tr * 4 + rr) * N + n0 + tc * 4]) = v;
    }
}

// ---------------------------------------------------------------------------
// Flash-style Euclidean-distance attention.
// q: [b][e][i] (e = h*64+d), kv: [b][n][e2] (k at e, v at 512+e)
// Block: 256 threads, one (bh, 64-query i-tile); loops 16 j-tiles of 64 keys.
// Row map: rows = tr + 16*rr (tr = t/16); cols = tc + 16*cc (tc = t%16).
// Strided col map keeps ks score reads at 2-way banks (free) instead of 8-way.
// ---------------------------------------------------------------------------
__global__ __launch_bounds__(256) void k_attn(const float* __restrict__ q,
                                              const float* __restrict__ kv,
                                              float* __restrict__ ao) {
    const int bh = blockIdx.y;
    const int b = bh >> 3, h = bh & 7;
    const int i0 = blockIdx.x * 64;
    const float* qb = q + (size_t)b * EINNER * XY + (size_t)h * DHEAD * XY;
    const float* kvb = kv + (size_t)b * NCTX * E2 + h * DHEAD;

    __shared__ float qs[64][68];
    __shared__ float ks[64][68];
    __shared__ float vs[64][68];
    __shared__ float pst[64][68];   // P transposed: [j][i-row]
    __shared__ float q2s[64], k2s[64];

    const int t = threadIdx.x;
    const int tr = t >> 4, tc = t & 15;

    // load Q tile (coalesced over i)
    {
        int r = t & 63, dl = t >> 6;
#pragma unroll
        for (int d = dl; d < 64; d += 4)
            qs[r][d] = qb[(size_t)d * XY + i0 + r];
    }
    __syncthreads();
    if (t < 64) {
        float ss = 0.f;
#pragma unroll 8
        for (int d = 0; d < 64; ++d) ss = fmaf(qs[t][d], qs[t][d], ss);
        q2s[t] = ss;
    }
    __syncthreads();

    float q2r[4];
#pragma unroll
    for (int rr = 0; rr < 4; ++rr) q2r[rr] = q2s[tr + 16 * rr];

    const float scale = 0.125f;   // 64^-0.5
    float m_run[4], l_run[4], o[4][4];
#pragma unroll
    for (int rr = 0; rr < 4; ++rr) {
        m_run[rr] = -INFINITY;
        l_run[rr] = 0.f;
#pragma unroll
        for (int cc = 0; cc < 4; ++cc) o[rr][cc] = 0.f;
    }

    for (int jt = 0; jt < 16; ++jt) {
        const int j0 = jt * 64;
        __syncthreads();   // prev PV done reading ks/vs/pst
        // load K/V tile (coalesced over d)
        {
            int d = t & 63, jl = t >> 6;
#pragma unroll
            for (int j = jl; j < 64; j += 4) {
                ks[j][d] = kvb[(size_t)(j0 + j) * E2 + d];
                vs[j][d] = kvb[(size_t)(j0 + j) * E2 + 512 + d];
            }
        }
        __syncthreads();
        if (t < 64) {
            float ss = 0.f;
#pragma unroll 8
            for (int d = 0; d < 64; ++d) ss = fmaf(ks[t][d], ks[t][d], ss);
            k2s[t] = ss;
        }
        __syncthreads();

        // scores: s[rr][cc] = q[row] . k[col]
        float s[4][4] = {};
#pragma unroll 2
        for (int dq = 0; dq < 16; ++dq) {
            float4 a[4], kq[4];
#pragma unroll
            for (int rr = 0; rr < 4; ++rr)
                a[rr] = *(const float4*)(&qs[tr + 16 * rr][dq * 4]);
#pragma unroll
            for (int cc = 0; cc < 4; ++cc)
                kq[cc] = *(const float4*)(&ks[tc + 16 * cc][dq * 4]);
#pragma unroll
            for (int rr = 0; rr < 4; ++rr)
#pragma unroll
                for (int cc = 0; cc < 4; ++cc) {
                    s[rr][cc] = fmaf(a[rr].x, kq[cc].x, s[rr][cc]);
                    s[rr][cc] = fmaf(a[rr].y, kq[cc].y, s[rr][cc]);
                    s[rr][cc] = fmaf(a[rr].z, kq[cc].z, s[rr][cc]);
                    s[rr][cc] = fmaf(a[rr].w, kq[cc].w, s[rr][cc]);
                }
        }

        // dist -> sim, online softmax per row (16 lanes per row group)
        float alpha[4];
#pragma unroll
        for (int rr = 0; rr < 4; ++rr) {
#pragma unroll
            for (int cc = 0; cc < 4; ++cc) {
                float d2 = q2r[rr] + k2s[tc + 16 * cc] - 2.f * s[rr][cc];
                s[rr][cc] = -scale * sqrtf(fmaxf(d2, 0.f));
            }
            float mt = fmaxf(fmaxf(s[rr][0], s[rr][1]), fmaxf(s[rr][2], s[rr][3]));
#pragma unroll
            for (int mk = 1; mk < 16; mk <<= 1) mt = fmaxf(mt, __shfl_xor(mt, mk, 64));
            float mn = fmaxf(m_run[rr], mt);
            alpha[rr] = __expf(m_run[rr] - mn);
            m_run[rr] = mn;
            float sum = 0.f;
#pragma unroll
            for (int cc = 0; cc < 4; ++cc) {
                float p = __expf(s[rr][cc] - mn);
                pst[tc + 16 * cc][tr + 16 * rr] = p;
                sum += p;
            }
#pragma unroll
            for (int mk = 1; mk < 16; mk <<= 1) sum += __shfl_xor(sum, mk, 64);
            l_run[rr] = l_run[rr] * alpha[rr] + sum;
#pragma unroll
            for (int cc = 0; cc < 4; ++cc) o[rr][cc] *= alpha[rr];
        }
        __syncthreads();   // pst visible

        // PV: o[row][dim], dims = tc*4+cc (contiguous -> float4 v reads)
#pragma unroll 4
        for (int j = 0; j < 64; ++j) {
            const float4 v4 = *(const float4*)(&vs[j][tc * 4]);
            float pj[4];
#pragma unroll
            for (int rr = 0; rr < 4; ++rr) pj[rr] = pst[j][tr + 16 * rr];
#pragma unroll
            for (int rr = 0; rr < 4; ++rr) {
                o[rr][0] = fmaf(pj[rr], v4.x, o[rr][0]);
                o[rr][1] = fmaf(pj[rr], v4.y, o[rr][1]);
                o[rr][2] = fmaf(pj[rr], v4.z, o[rr][2]);
                o[rr][3] = fmaf(pj[rr], v4.w, o[rr][3]);
            }
        }
    }

    // normalize + write out via LDS transpose (reuse qs)
    float inv[4];
#pragma unroll
    for (int rr = 0; rr < 4; ++rr) inv[rr] = 1.f / l_run[rr];
    __syncthreads();
#pragma unroll
    for (int rr = 0; rr < 4; ++rr) {
        float4 v = {o[rr][0] * inv[rr], o[rr][1] * inv[rr],
                    o[rr][2] * inv[rr], o[rr][3] * inv[rr]};
        *(float4*)(&qs[tr + 16 * rr][tc * 4]) = v;
    }
    __syncthreads();
    {
        int r = t & 63, dl = t >> 6;
#pragma unroll
        for (int d = dl; d < 64; d += 4)
            ao[(size_t)b * EINNER * XY + (size_t)(h * DHEAD + d) * XY + i0 + r] = qs[r][d];
    }
}

// ---------------------------------------------------------------------------
extern "C" void kernel_launch(void* const* d_in, const int* in_sizes, int n_in,
                              void* d_out, int out_size, void* d_ws, size_t ws_size,
                              hipStream_t stream) {
    const float* fmap    = (const float*)d_in[0];
    const float* context = (const float*)d_in[1];
    const float* gfm     = (const float*)d_in[2];
    const float* gctx    = (const float*)d_in[3];
    const float* Wq      = (const float*)d_in[4];
    const float* Wkv     = (const float*)d_in[5];
    const float* Wout    = (const float*)d_in[6];
    float* out = (float*)d_out;

    float* ws = (float*)d_ws;
    float* fscale = ws;                    //   8192
    float* cscale = ws + 8192;             //   8192
    float* qbuf   = ws + 16384;            // 4,194,304  q[b][e][xy]
    float* kvbuf  = qbuf + 4194304;        // 8,388,608  kv[b][n][e2]
    float* aobuf  = kvbuf + 8388608;       // 4,194,304  attnout[b][e][xy]
    // total ws: ~67.2 MB of floats

    k_fmap_scale<<<32, 256, 0, stream>>>(fmap, fscale);
    k_ctx_scale<<<2048, 256, 0, stream>>>(context, cscale);

    // q[b][e][xy] = Wq[e][c] * (fmap[b][c][xy] * fscale[b][xy] * gfm[c])
    k_gemm_nn<true><<<dim3(16, 8, BATCH), 256, 0, stream>>>(
        Wq, fmap, qbuf, fscale, gfm, EINNER, XY, CDIM);

    // kv[b][n][e2] = (ctx[b][n][c] * cscale[b][n] * gctx[c]) * Wkv[e2][c]^T
    k_gemm_nt<<<dim3(16, 16, BATCH), 256, 0, stream>>>(
        context, Wkv, kvbuf, cscale, gctx, NCTX, E2, CDIM);

    // attention
    k_attn<<<dim3(16, 64), 256, 0, stream>>>(qbuf, kvbuf, aobuf);

    // out[b][d][xy] = Wout[d][e] * aobuf[b][e][xy]
    k_gemm_nn<false><<<dim3(16, 8, BATCH), 256, 0, stream>>>(
        Wout, aobuf, out, nullptr, nullptr, CDIM, XY, EINNER);
}

// Round 3
// 601.321 us; speedup vs baseline: 1.2733x; 1.2733x over previous
//
#include <hip/hip_runtime.h>
#include <math.h>

// Problem constants
#define BATCH 8
#define CDIM 512       // DIM
#define XY 1024        // X*Y = 32*32
#define NCTX 1024
#define HEADS 8
#define DHEAD 64
#define EINNER 512     // HEADS*DHEAD
#define E2 1024        // 2*EINNER

#define SQRT_DIM 22.627416997969522f  // sqrt(512)

typedef short bf16x8 __attribute__((ext_vector_type(8)));
typedef float f32x4 __attribute__((ext_vector_type(4)));
typedef unsigned short ushort4v __attribute__((ext_vector_type(4)));

// float -> bf16 bits (RNE)
__device__ __forceinline__ unsigned short f2bf(float x) {
    unsigned int u = __builtin_bit_cast(unsigned int, x);
    return (unsigned short)((u + 0x7fffu + ((u >> 16) & 1u)) >> 16);
}
__device__ __forceinline__ float bf2f(unsigned short h) {
    unsigned int u = ((unsigned int)h) << 16;
    return __builtin_bit_cast(float, u);
}

// ---------------------------------------------------------------------------
// Kernel 1: per-(b,xy) channel-RMSNorm scale for fmap  [b][c][xy]
// ---------------------------------------------------------------------------
__global__ __launch_bounds__(256) void k_fmap_scale(const float* __restrict__ fmap,
                                                    float* __restrict__ fscale) {
    int t = blockIdx.x * 256 + threadIdx.x;       // 0..8191 = B*XY
    int b = t >> 10;
    const float* p = fmap + (size_t)b * CDIM * XY + (t & 1023);
    float ss = 0.f;
#pragma unroll 8
    for (int c = 0; c < CDIM; ++c) {
        float v = p[(size_t)c * XY];
        ss = fmaf(v, v, ss);
    }
    fscale[t] = SQRT_DIM / fmaxf(sqrtf(ss), 1e-12f);
}

// ---------------------------------------------------------------------------
// Kernel 2: per-(b,n) RMSNorm scale for context [b][n][c]
// ---------------------------------------------------------------------------
__global__ __launch_bounds__(256) void k_ctx_scale(const float* __restrict__ ctx,
                                                   float* __restrict__ cscale) {
    int row = blockIdx.x * 4 + (threadIdx.x >> 6);
    int lane = threadIdx.x & 63;
    const float* p = ctx + (size_t)row * CDIM;
    float ss = 0.f;
#pragma unroll
    for (int k = 0; k < CDIM / 64; ++k) {
        float v = p[lane + 64 * k];
        ss = fmaf(v, v, ss);
    }
#pragma unroll
    for (int off = 32; off; off >>= 1) ss += __shfl_down(ss, off, 64);
    if (lane == 0) cscale[row] = SQRT_DIM / fmaxf(sqrtf(ss), 1e-12f);
}

// ---------------------------------------------------------------------------
// GEMM NN: C[b][m][n] = sum_k A[m][k] * Bop[b][k][n]   (fp32, 64x64 tile)
// ---------------------------------------------------------------------------
template <bool SCALE_B>
__global__ __launch_bounds__(256) void k_gemm_nn(const float* __restrict__ A,
                                                 const float* __restrict__ Bm,
                                                 float* __restrict__ Cm,
                                                 const float* __restrict__ colscale,
                                                 const float* __restrict__ rowgamma,
                                                 int M, int N, int K) {
    const int b = blockIdx.z;
    const int n0 = blockIdx.x * 64, m0 = blockIdx.y * 64;
    const float* Bb = Bm + (size_t)b * K * N;
    float* Cb = Cm + (size_t)b * M * N;
    __shared__ float As[16][68];
    __shared__ float Bs[16][68];
    const int t = threadIdx.x;
    const int tr = t >> 4, tc = t & 15;
    const int la_k = t & 15, la_m = t >> 4;
    const int lb_n = t & 63, lb_k = t >> 6;
    float acc[4][4] = {};

    float cs = 1.f;
    if constexpr (SCALE_B) cs = colscale[(size_t)b * N + n0 + lb_n];

    for (int k0 = 0; k0 < K; k0 += 16) {
        __syncthreads();
#pragma unroll
        for (int i = 0; i < 4; ++i) {
            int m = la_m + 16 * i;
            As[la_k][m] = A[(size_t)(m0 + m) * K + k0 + la_k];
        }
#pragma unroll
        for (int i = 0; i < 4; ++i) {
            int kk = lb_k + 4 * i;
            float v = Bb[(size_t)(k0 + kk) * N + n0 + lb_n];
            if constexpr (SCALE_B) v *= cs * rowgamma[k0 + kk];
            Bs[kk][lb_n] = v;
        }
        __syncthreads();
#pragma unroll
        for (int kk = 0; kk < 16; ++kk) {
            const float4 a4 = *(const float4*)(&As[kk][tr * 4]);
            const float4 b4 = *(const float4*)(&Bs[kk][tc * 4]);
            const float ar[4] = {a4.x, a4.y, a4.z, a4.w};
            const float bc[4] = {b4.x, b4.y, b4.z, b4.w};
#pragma unroll
            for (int rr = 0; rr < 4; ++rr)
#pragma unroll
                for (int cc = 0; cc < 4; ++cc)
                    acc[rr][cc] = fmaf(ar[rr], bc[cc], acc[rr][cc]);
        }
    }
#pragma unroll
    for (int rr = 0; rr < 4; ++rr) {
        float4 v = {acc[rr][0], acc[rr][1], acc[rr][2], acc[rr][3]};
        *(float4*)(&Cb[(size_t)(m0 + tr * 4 + rr) * N + n0 + tc * 4]) = v;
    }
}

// ---------------------------------------------------------------------------
// KV projection GEMM (NT) with bf16 hi/lo split epilogue.
// A = context [b][n][c] (scaled by cscale[n]*gctx[c]); B = Wkv [e2][c].
// Outputs: khi/klo [bh][n][64], vthi/vtlo [bh][64][n] (V transposed), k2[bh][n]
// ---------------------------------------------------------------------------
__global__ __launch_bounds__(256) void k_gemm_kv(const float* __restrict__ Am,
                                                 const float* __restrict__ Bmat,
                                                 const float* __restrict__ rowscale,
                                                 const float* __restrict__ kgamma,
                                                 unsigned short* __restrict__ khi,
                                                 unsigned short* __restrict__ klo,
                                                 unsigned short* __restrict__ vthi,
                                                 unsigned short* __restrict__ vtlo,
                                                 float* __restrict__ k2g) {
    const int b = blockIdx.z;
    const int M = NCTX, K = CDIM;
    const int n0 = blockIdx.x * 64, m0 = blockIdx.y * 64;
    const float* Ab = Am + (size_t)b * M * K;
    __shared__ float As[16][68];
    __shared__ float Bs[16][68];
    const int t = threadIdx.x;
    const int tr = t >> 4, tc = t & 15;
    const int la_k = t & 15, la_m = t >> 4;
    float acc[4][4] = {};

    float rs[4];
#pragma unroll
    for (int i = 0; i < 4; ++i)
        rs[i] = rowscale[(size_t)b * M + m0 + la_m + 16 * i];

    for (int k0 = 0; k0 < K; k0 += 16) {
        __syncthreads();
#pragma unroll
        for (int i = 0; i < 4; ++i) {
            int m = la_m + 16 * i;
            float v = Ab[(size_t)(m0 + m) * K + k0 + la_k];
            v *= rs[i] * kgamma[k0 + la_k];
            As[la_k][m] = v;
        }
#pragma unroll
        for (int i = 0; i < 4; ++i) {
            int n = la_m + 16 * i;
            Bs[la_k][n] = Bmat[(size_t)(n0 + n) * K + k0 + la_k];
        }
        __syncthreads();
#pragma unroll
        for (int kk = 0; kk < 16; ++kk) {
            const float4 a4 = *(const float4*)(&As[kk][tr * 4]);
            const float4 b4 = *(const float4*)(&Bs[kk][tc * 4]);
            const float ar[4] = {a4.x, a4.y, a4.z, a4.w};
            const float bc[4] = {b4.x, b4.y, b4.z, b4.w};
#pragma unroll
            for (int rr = 0; rr < 4; ++rr)
#pragma unroll
                for (int cc = 0; cc < 4; ++cc)
                    acc[rr][cc] = fmaf(ar[rr], bc[cc], acc[rr][cc]);
        }
    }

    // epilogue: split to bf16 hi/lo, frag-ready layouts
    const int hh = (n0 >> 6) & 7;
    const int bh_i = b * 8 + hh;
    if (n0 < EINNER) {
        // K half: [bh][n][d], d = tc*4+cc
#pragma unroll
        for (int rr = 0; rr < 4; ++rr) {
            const int n = m0 + tr * 4 + rr;
            ushort4v h4, l4;
#pragma unroll
            for (int cc = 0; cc < 4; ++cc) {
                unsigned short h = f2bf(acc[rr][cc]);
                h4[cc] = h;
                l4[cc] = f2bf(acc[rr][cc] - bf2f(h));
            }
            *(ushort4v*)(khi + ((size_t)bh_i * NCTX + n) * 64 + tc * 4) = h4;
            *(ushort4v*)(klo + ((size_t)bh_i * NCTX + n) * 64 + tc * 4) = l4;
        }
        // k2 = sum_d k^2 (fp32)
#pragma unroll
        for (int rr = 0; rr < 4; ++rr) {
            float s = 0.f;
#pragma unroll
            for (int cc = 0; cc < 4; ++cc) s = fmaf(acc[rr][cc], acc[rr][cc], s);
            s += __shfl_xor(s, 1, 64);
            s += __shfl_xor(s, 2, 64);
            s += __shfl_xor(s, 4, 64);
            s += __shfl_xor(s, 8, 64);
            if (tc == 0) k2g[(size_t)bh_i * NCTX + m0 + tr * 4 + rr] = s;
        }
    } else {
        // V half: transposed [bh][d][n], d = tc*4+cc
#pragma unroll
        for (int cc = 0; cc < 4; ++cc) {
            const int d = tc * 4 + cc;
            ushort4v h4, l4;
#pragma unroll
            for (int rr = 0; rr < 4; ++rr) {
                unsigned short h = f2bf(acc[rr][cc]);
                h4[rr] = h;
                l4[rr] = f2bf(acc[rr][cc] - bf2f(h));
            }
            *(ushort4v*)(vthi + ((size_t)bh_i * 64 + d) * NCTX + m0 + tr * 4) = h4;
            *(ushort4v*)(vtlo + ((size_t)bh_i * 64 + d) * NCTX + m0 + tr * 4) = l4;
        }
    }
}

// ---------------------------------------------------------------------------
// MFMA flash attention (Euclidean-distance scores), split-bf16 precision.
// Block: 256 thr = 4 waves; each wave owns 16 q-rows of a 64-query i-tile.
// Per j-tile (64 keys): S = QK^T via 6 mfma/coltile (hi*hi+hi*lo+lo*hi, K=64),
// online softmax (16-lane shfl), P split->per-wave LDS, PV via 6 mfma/dtile.
// No __syncthreads in the j-loop (per-wave-private LDS only).
// C/D layout (HW-verified): row = 4*(lane>>4)+reg, col = lane&15.
// A/B frag k-map need only be mutually consistent (dot is perm-invariant).
// ---------------------------------------------------------------------------
__global__ __launch_bounds__(256) void k_attn_mfma(
    const float* __restrict__ qbuf, const unsigned short* __restrict__ khi,
    const unsigned short* __restrict__ klo, const unsigned short* __restrict__ vthi,
    const unsigned short* __restrict__ vtlo, const float* __restrict__ k2g,
    float* __restrict__ ao) {
    const int bh = blockIdx.y;
    const int i0 = blockIdx.x * 64;
    const int t = threadIdx.x;
    const int w = t >> 6;
    const int lane = t & 63;
    const int c = lane & 15, g = lane >> 4;

    // pool: per-wave P staging [16][72] ushort x2 (4608B/wave), reused as
    // [64][68] f32 for the output transpose at the end.
    __shared__ __align__(16) char pool[18432];
    unsigned short* psth = (unsigned short*)(pool + w * 4608);   // [16][72]
    unsigned short* pstl = psth + 16 * 72;
    __shared__ float q2s[64];

    // ---- Q setup: direct global loads, fp32 ----
    const float* qb = qbuf + (size_t)bh * 64 * XY;
    const int qrow = i0 + 16 * w + c;
    float qv[16];
#pragma unroll
    for (int kk = 0; kk < 2; ++kk)
#pragma unroll
        for (int i = 0; i < 8; ++i)
            qv[kk * 8 + i] = qb[(size_t)(32 * kk + 8 * g + i) * XY + qrow];

    float s2 = 0.f;
#pragma unroll
    for (int i = 0; i < 16; ++i) s2 = fmaf(qv[i], qv[i], s2);
    s2 += __shfl_xor(s2, 16, 64);
    s2 += __shfl_xor(s2, 32, 64);
    if (g == 0) q2s[16 * w + c] = s2;
    __syncthreads();
    float q2r[4];
#pragma unroll
    for (int r = 0; r < 4; ++r) q2r[r] = q2s[16 * w + 4 * g + r];

    bf16x8 qh[2], ql[2];
#pragma unroll
    for (int kk = 0; kk < 2; ++kk)
#pragma unroll
        for (int i = 0; i < 8; ++i) {
            float x = qv[kk * 8 + i];
            unsigned short h = f2bf(x);
            qh[kk][i] = (short)h;
            ql[kk][i] = (short)f2bf(x - bf2f(h));
        }

    const unsigned short* khb = khi + (size_t)bh * NCTX * 64;
    const unsigned short* klb = klo + (size_t)bh * NCTX * 64;
    const unsigned short* vhb = vthi + (size_t)bh * 64 * NCTX;
    const unsigned short* vlb = vtlo + (size_t)bh * 64 * NCTX;
    const float* k2b = k2g + (size_t)bh * NCTX;

    f32x4 acc_o[4] = {{0.f, 0.f, 0.f, 0.f}, {0.f, 0.f, 0.f, 0.f},
                      {0.f, 0.f, 0.f, 0.f}, {0.f, 0.f, 0.f, 0.f}};
    float m_run[4], l_run[4];
#pragma unroll
    for (int r = 0; r < 4; ++r) { m_run[r] = -1e30f; l_run[r] = 0.f; }

    for (int j0 = 0; j0 < NCTX; j0 += 64) {
        float p[4][4];
        // ---- scores: 4 col-tiles of 16 keys ----
#pragma unroll
        for (int cc = 0; cc < 4; ++cc) {
            const unsigned short* kr_h = khb + (size_t)(j0 + 16 * cc + c) * 64 + 8 * g;
            const unsigned short* kr_l = klb + (size_t)(j0 + 16 * cc + c) * 64 + 8 * g;
            f32x4 acc = {0.f, 0.f, 0.f, 0.f};
#pragma unroll
            for (int kk = 0; kk < 2; ++kk) {
                bf16x8 kh_ = *(const bf16x8*)(kr_h + 32 * kk);
                bf16x8 kl_ = *(const bf16x8*)(kr_l + 32 * kk);
                acc = __builtin_amdgcn_mfma_f32_16x16x32_bf16(qh[kk], kh_, acc, 0, 0, 0);
                acc = __builtin_amdgcn_mfma_f32_16x16x32_bf16(qh[kk], kl_, acc, 0, 0, 0);
                acc = __builtin_amdgcn_mfma_f32_16x16x32_bf16(ql[kk], kh_, acc, 0, 0, 0);
            }
            float k2v = k2b[j0 + 16 * cc + c];
#pragma unroll
            for (int r = 0; r < 4; ++r) {
                float d2 = q2r[r] + k2v - 2.f * acc[r];
                p[cc][r] = -0.125f * sqrtf(fmaxf(d2, 0.f));
            }
        }
        // ---- online softmax (rows = 4g+r, 16 lanes per row) ----
        float alpha[4];
#pragma unroll
        for (int r = 0; r < 4; ++r) {
            float mt = fmaxf(fmaxf(p[0][r], p[1][r]), fmaxf(p[2][r], p[3][r]));
            mt = fmaxf(mt, __shfl_xor(mt, 1, 64));
            mt = fmaxf(mt, __shfl_xor(mt, 2, 64));
            mt = fmaxf(mt, __shfl_xor(mt, 4, 64));
            mt = fmaxf(mt, __shfl_xor(mt, 8, 64));
            float mn = fmaxf(m_run[r], mt);
            alpha[r] = __expf(m_run[r] - mn);
            m_run[r] = mn;
            float sum = 0.f;
#pragma unroll
            for (int cc = 0; cc < 4; ++cc) {
                float e = __expf(p[cc][r] - mn);
                p[cc][r] = e;
                sum += e;
            }
            sum += __shfl_xor(sum, 1, 64);
            sum += __shfl_xor(sum, 2, 64);
            sum += __shfl_xor(sum, 4, 64);
            sum += __shfl_xor(sum, 8, 64);
            l_run[r] = l_run[r] * alpha[r] + sum;
        }
#pragma unroll
        for (int dt = 0; dt < 4; ++dt)
#pragma unroll
            for (int r = 0; r < 4; ++r) acc_o[dt][r] *= alpha[r];

        // ---- stage split P to per-wave LDS (row = 4g+r, col = 16cc+c) ----
#pragma unroll
        for (int cc = 0; cc < 4; ++cc)
#pragma unroll
            for (int r = 0; r < 4; ++r) {
                float x = p[cc][r];
                unsigned short h = f2bf(x);
                psth[(4 * g + r) * 72 + 16 * cc + c] = h;
                pstl[(4 * g + r) * 72 + 16 * cc + c] = f2bf(x - bf2f(h));
            }
        asm volatile("s_waitcnt lgkmcnt(0)" ::: "memory");
        bf16x8 ph[2], pl[2];
#pragma unroll
        for (int kk = 0; kk < 2; ++kk) {
            ph[kk] = *(const bf16x8*)(psth + c * 72 + 32 * kk + 8 * g);
            pl[kk] = *(const bf16x8*)(pstl + c * 72 + 32 * kk + 8 * g);
        }
        // ---- PV: 4 d-tiles ----
#pragma unroll
        for (int dt = 0; dt < 4; ++dt) {
            const unsigned short* vr_h = vhb + (size_t)(16 * dt + c) * NCTX + j0 + 8 * g;
            const unsigned short* vr_l = vlb + (size_t)(16 * dt + c) * NCTX + j0 + 8 * g;
#pragma unroll
            for (int kk = 0; kk < 2; ++kk) {
                bf16x8 vh_ = *(const bf16x8*)(vr_h + 32 * kk);
                bf16x8 vl_ = *(const bf16x8*)(vr_l + 32 * kk);
                acc_o[dt] = __builtin_amdgcn_mfma_f32_16x16x32_bf16(ph[kk], vh_, acc_o[dt], 0, 0, 0);
                acc_o[dt] = __builtin_amdgcn_mfma_f32_16x16x32_bf16(ph[kk], vl_, acc_o[dt], 0, 0, 0);
                acc_o[dt] = __builtin_amdgcn_mfma_f32_16x16x32_bf16(pl[kk], vh_, acc_o[dt], 0, 0, 0);
            }
        }
    }

    // ---- normalize + transpose via LDS + coalesced store ----
    float inv[4];
#pragma unroll
    for (int r = 0; r < 4; ++r) inv[r] = 1.f / l_run[r];
    __syncthreads();   // all waves done with their pst regions
    float* tp = (float*)pool;   // [64][68]
#pragma unroll
    for (int dt = 0; dt < 4; ++dt)
#pragma unroll
        for (int r = 0; r < 4; ++r)
            tp[(16 * w + 4 * g + r) * 68 + 16 * dt + c] = acc_o[dt][r] * inv[r];
    __syncthreads();
    const int q = t & 63;
#pragma unroll
    for (int dd = 0; dd < 16; ++dd) {
        int d = (t >> 6) * 16 + dd;
        ao[((size_t)bh * 64 + d) * XY + i0 + q] = tp[q * 68 + d];
    }
}

// ---------------------------------------------------------------------------
extern "C" void kernel_launch(void* const* d_in, const int* in_sizes, int n_in,
                              void* d_out, int out_size, void* d_ws, size_t ws_size,
                              hipStream_t stream) {
    const float* fmap    = (const float*)d_in[0];
    const float* context = (const float*)d_in[1];
    const float* gfm     = (const float*)d_in[2];
    const float* gctx    = (const float*)d_in[3];
    const float* Wq      = (const float*)d_in[4];
    const float* Wkv     = (const float*)d_in[5];
    const float* Wout    = (const float*)d_in[6];
    float* out = (float*)d_out;

    float* ws = (float*)d_ws;
    float* fscale = ws;                               //     8,192 f32
    float* cscale = ws + 8192;                        //     8,192 f32
    float* qbuf   = ws + 16384;                       // 4,194,304 f32 (q; reused as attn-out)
    float* k2g    = ws + 16384 + 4194304;             //    65,536 f32
    unsigned short* khi  = (unsigned short*)(ws + 16384 + 4194304 + 65536);
    unsigned short* klo  = khi + 4194304;             // each 4M ushort = 8 MB
    unsigned short* vthi = klo + 4194304;
    unsigned short* vtlo = vthi + 4194304;
    // total ws usage ~50.7 MB (was 67.2 MB)

    k_fmap_scale<<<32, 256, 0, stream>>>(fmap, fscale);
    k_ctx_scale<<<2048, 256, 0, stream>>>(context, cscale);

    // q[b][e][xy] = Wq[e][c] * (fmap[b][c][xy] * fscale[b][xy] * gfm[c])
    k_gemm_nn<true><<<dim3(16, 8, BATCH), 256, 0, stream>>>(
        Wq, fmap, qbuf, fscale, gfm, EINNER, XY, CDIM);

    // KV projection -> bf16 hi/lo frag-ready buffers + k2
    k_gemm_kv<<<dim3(16, 16, BATCH), 256, 0, stream>>>(
        context, Wkv, cscale, gctx, khi, klo, vthi, vtlo, k2g);

    // MFMA attention; output written in-place over qbuf
    k_attn_mfma<<<dim3(16, 64), 256, 0, stream>>>(
        qbuf, khi, klo, vthi, vtlo, k2g, qbuf);

    // out[b][d][xy] = Wout[d][e] * attnout[b][e][xy]
    k_gemm_nn<false><<<dim3(16, 8, BATCH), 256, 0, stream>>>(
        Wout, qbuf, out, nullptr, nullptr, CDIM, XY, EINNER);
}